// Round 3
// baseline (692.372 us; speedup 1.0000x reference)
//
#include <hip/hip_runtime.h>
#include <cstdint>
#include <cstddef>

typedef unsigned short u16;
typedef unsigned int   u32;
typedef short s16x8 __attribute__((ext_vector_type(8)));   // 8 bf16 bit-patterns (4 VGPRs)
typedef float f32x4 __attribute__((ext_vector_type(4)));

#define B_   4
#define H_   16
#define N_   2048
#define M_   2048
#define D_   1024
#define ROWS 8192   // B_*N_ == B_*M_

// ---------- scalar helpers ----------
__device__ __forceinline__ u16 f2bf(float x){
  u32 u = __builtin_bit_cast(u32, x);
  u = (u + 0x7fffu + ((u >> 16) & 1u)) >> 16;   // RNE truncate to bf16
  return (u16)u;
}
__device__ __forceinline__ float bf2f(u16 h){
  u32 u = ((u32)h) << 16;
  return __builtin_bit_cast(float, u);
}
__device__ __forceinline__ void split2(float v, u16 &h, u16 &l){
  h = f2bf(v);
  l = f2bf(v - bf2f(h));
}
__device__ __forceinline__ void gload16(const void* g, void* l){
  __builtin_amdgcn_global_load_lds((const __attribute__((address_space(1))) u32*)g,
                                   (__attribute__((address_space(3))) u32*)l, 16, 0, 0);
}
__device__ __forceinline__ f32x4 mfma16(s16x8 a, s16x8 b, f32x4 c){
  return __builtin_amdgcn_mfma_f32_16x16x32_bf16(a, b, c, 0, 0, 0);
}

// ---------- kernel 1: split X and M into bf16 hi/lo ----------
__global__ void split_xm(const float* __restrict__ X, const float* __restrict__ Mi,
                         u16* __restrict__ Xh, u16* __restrict__ Xl,
                         u16* __restrict__ Mh, u16* __restrict__ Ml){
  const int n4 = ROWS * D_ / 4;
  for (int i = blockIdx.x * blockDim.x + threadIdx.x; i < n4; i += gridDim.x * blockDim.x){
    float4 x = ((const float4*)X)[i];
    float4 m = ((const float4*)Mi)[i];
    ushort4 xh, xl, mh, ml;
    split2(x.x, xh.x, xl.x); split2(x.y, xh.y, xl.y);
    split2(x.z, xh.z, xl.z); split2(x.w, xh.w, xl.w);
    split2(m.x, mh.x, ml.x); split2(m.y, mh.y, ml.y);
    split2(m.z, mh.z, ml.z); split2(m.w, mh.w, ml.w);
    ((ushort4*)Xh)[i] = xh; ((ushort4*)Xl)[i] = xl;
    ((ushort4*)Mh)[i] = mh; ((ushort4*)Ml)[i] = ml;
  }
}

// ---------- kernel 2: weight transposes + hi/lo splits ----------
// PqT[c][d]  = P_q[c>>6][d][c&63]      (c = h*64+k), 1024x1024
// PkvT[c][d] = c<64 ? P_k[d][c] : P_v[d][c-64]        128x1024
// WoT[d][hv] = P_o[hv>>6][d][hv&63]                  1024x1024
__global__ void transform_w(const float* __restrict__ Pq, const float* __restrict__ Pk,
                            const float* __restrict__ Pv, const float* __restrict__ Po,
                            u16* __restrict__ PqTh, u16* __restrict__ PqTl,
                            u16* __restrict__ PkvTh, u16* __restrict__ PkvTl,
                            u16* __restrict__ WoTh, u16* __restrict__ WoTl){
  const int TOT = 1048576 + 131072 + 1048576;
  for (int gid = blockIdx.x * blockDim.x + threadIdx.x; gid < TOT; gid += gridDim.x * blockDim.x){
    float v; u16 *oh, *ol; int oidx;
    if (gid < 1048576){
      int c = gid >> 10, d = gid & 1023;
      v = Pq[(size_t)(c >> 6) * 65536 + d * 64 + (c & 63)];
      oh = PqTh; ol = PqTl; oidx = gid;
    } else if (gid < 1048576 + 131072){
      int t = gid - 1048576; int c = t >> 10, d = t & 1023;
      v = (c < 64) ? Pk[d * 64 + c] : Pv[d * 64 + (c - 64)];
      oh = PkvTh; ol = PkvTl; oidx = t;
    } else {
      int t = gid - (1048576 + 131072); int dd = t >> 10, hv = t & 1023;
      v = Po[(size_t)(hv >> 6) * 65536 + dd * 64 + (hv & 63)];
      oh = WoTh; ol = WoTl; oidx = t;
    }
    u16 h, l; split2(v, h, l);
    oh[oidx] = h; ol[oidx] = l;
  }
}

// ---------- shared GEMM: C(8192 x NCOLS) = A(8192x1024) * BT(NCOLS x 1024)^T ----------
// split-3: Ah*Bh + Ah*Bl + Al*Bh, fp32 accum. 128x128 tile, BK=32, 4 waves (2x2).
// MODE 0: out Q hi/lo in (b,h,n,k). MODE 1: cols<64 -> K hi/lo (b,m,k); cols>=64 -> VT bf16 (b,v,m).
// MODE 2: out fp32 row-major (Y).
template<int MODE>
__global__ __launch_bounds__(256, 2)
void gemm3(const u16* __restrict__ Ah, const u16* __restrict__ Al,
           const u16* __restrict__ Bh, const u16* __restrict__ Bl,
           void* __restrict__ o0, void* __restrict__ o1, void* __restrict__ o2){
  __shared__ __align__(16) u16 lds[2][4][128 * 32];
  const int tid = threadIdx.x;
  const int lane = tid & 63;
  const int w = tid >> 6;
  const int wr = w >> 1, wc = w & 1;
  const int br0 = blockIdx.y * 128;
  const int bc0 = blockIdx.x * 128;

  const u16* srcs[4] = {Ah, Al, Bh, Bl};

  auto stage = [&](int buf, int s){
    const int k0 = s * 32;
#pragma unroll
    for (int t = 0; t < 4; t++){
      const u16* src = srcs[t];
      const int rbase = (t >= 2) ? bc0 : br0;
#pragma unroll
      for (int it = 0; it < 2; it++){
        const int c1k = w * 2 + it;             // 1KB chunk 0..7 within the 8KB tile
        const int ci = c1k * 64 + lane;         // 16B chunk 0..511
        const int row = ci >> 2;
        const int gs = (ci & 3) ^ ((row >> 1) & 3);   // pre-swizzled global source
        gload16(src + (size_t)(rbase + row) * 1024 + k0 + gs * 8,
                &lds[buf][t][c1k * 512]);
      }
    }
  };

  f32x4 acc[4][4];
#pragma unroll
  for (int i = 0; i < 4; i++)
#pragma unroll
    for (int j = 0; j < 4; j++) acc[i][j] = f32x4{0.f, 0.f, 0.f, 0.f};

  stage(0, 0);
  for (int s = 0; s < 32; s++){
    __syncthreads();                 // compiler drains vmcnt+lgkmcnt before s_barrier
    if (s + 1 < 32) stage((s + 1) & 1, s + 1);
    const int buf = s & 1;
    const int g = lane >> 4;
    s16x8 fah[4], fal[4], fbh[4], fbl[4];
#pragma unroll
    for (int i = 0; i < 4; i++){
      const int ra = wr * 64 + i * 16 + (lane & 15);
      const int oa = ra * 64 + ((g ^ ((ra >> 1) & 3)) * 16);
      fah[i] = *(const s16x8*)((const char*)&lds[buf][0][0] + oa);
      fal[i] = *(const s16x8*)((const char*)&lds[buf][1][0] + oa);
      const int rb = wc * 64 + i * 16 + (lane & 15);
      const int ob = rb * 64 + ((g ^ ((rb >> 1) & 3)) * 16);
      fbh[i] = *(const s16x8*)((const char*)&lds[buf][2][0] + ob);
      fbl[i] = *(const s16x8*)((const char*)&lds[buf][3][0] + ob);
    }
#pragma unroll
    for (int i = 0; i < 4; i++)
#pragma unroll
      for (int j = 0; j < 4; j++){
        acc[i][j] = mfma16(fah[i], fbh[j], acc[i][j]);
        acc[i][j] = mfma16(fah[i], fbl[j], acc[i][j]);
        acc[i][j] = mfma16(fal[i], fbh[j], acc[i][j]);
      }
  }

#pragma unroll
  for (int i = 0; i < 4; i++){
#pragma unroll
    for (int j = 0; j < 4; j++){
#pragma unroll
      for (int r = 0; r < 4; r++){
        const int row = br0 + wr * 64 + i * 16 + (lane >> 4) * 4 + r;
        const int col = bc0 + wc * 64 + j * 16 + (lane & 15);
        const float v = acc[i][j][r];
        if (MODE == 0){
          const int b = row >> 11, n = row & 2047;
          const int h = col >> 6,  k = col & 63;
          const size_t idx = ((size_t)(b * H_ + h) * N_ + n) * 64 + k;
          u16 hh, ll; split2(v, hh, ll);
          ((u16*)o0)[idx] = hh; ((u16*)o1)[idx] = ll;
        } else if (MODE == 1){
          if (col < 64){
            const size_t idx = (size_t)row * 64 + col;
            u16 hh, ll; split2(v, hh, ll);
            ((u16*)o0)[idx] = hh; ((u16*)o1)[idx] = ll;
          } else {
            const int b = row >> 11, m = row & 2047;
            const size_t idx = (size_t)b * (64 * 2048) + (size_t)(col - 64) * 2048 + m;
            ((u16*)o2)[idx] = f2bf(v);
          }
        } else {
          ((float*)o0)[(size_t)row * 1024 + col] = v;
        }
      }
    }
  }
}

// ---------- kernel 5: flash attention ----------
// block = 4 waves; wave owns 32 q-rows of one (b,h); loops m in steps of 32.
// S = Q*K^T via split-3 (6 mfma / 16x16 tile), +mask, online softmax, P*V in bf16.
// Block mapping: 16 consecutive-dispatch-residue blocks = the 16 heads of one (b,qb)
// group, packed onto one XCD (dispatch id ≡ g mod 8) so mask slab + K/V are L2-shared.
__global__ __launch_bounds__(256)
void attn(const u16* __restrict__ Qh, const u16* __restrict__ Ql,
          const u16* __restrict__ Kh, const u16* __restrict__ Kl,
          const u16* __restrict__ VT, const float* __restrict__ mask,
          u16* __restrict__ Oh, u16* __restrict__ Ol){
  __shared__ __align__(16) u16 plds[4][32 * 40];   // per-wave P scratch, stride 40 u16 (16B-aligned rows)
  const int lane = threadIdx.x & 63;
  const int w = threadIdx.x >> 6;
  // XCD-grouped decode: d = (g&7) + 8*(16*(g>>3) + h), bijective over 1024
  const int r8 = blockIdx.x & 7;
  const int q8 = blockIdx.x >> 3;          // 0..127
  const int h  = q8 & 15;                  // head (within-group index)
  const int g  = (q8 >> 4) * 8 + r8;       // group 0..63 = b*16+qb
  const int b  = g >> 4, qb = g & 15;
  const int q0 = qb * 128 + w * 32;

  const u16* qbh = Qh + ((size_t)(b * H_ + h) * N_) * 64;
  const u16* qbl = Ql + ((size_t)(b * H_ + h) * N_) * 64;
  const u16* kbh = Kh + (size_t)b * M_ * 64;
  const u16* kbl = Kl + (size_t)b * M_ * 64;
  const u16* vtb = VT + (size_t)b * 64 * M_;
  const float* mkb = mask + (size_t)b * N_ * M_;
  u16* pl = &plds[w][0];

  // Q fragments: [qt][kc], A-frag layout (row = lane&15, k = (lane>>4)*8+i)
  s16x8 fqh[2][2], fql[2][2];
#pragma unroll
  for (int qt = 0; qt < 2; qt++)
#pragma unroll
    for (int kc = 0; kc < 2; kc++){
      const int row = q0 + qt * 16 + (lane & 15);
      const size_t off = (size_t)row * 64 + kc * 32 + (lane >> 4) * 8;
      fqh[qt][kc] = *(const s16x8*)(qbh + off);
      fql[qt][kc] = *(const s16x8*)(qbl + off);
    }

  f32x4 acc[2][4];   // [qt][vt]
#pragma unroll
  for (int qt = 0; qt < 2; qt++)
#pragma unroll
    for (int vt = 0; vt < 4; vt++) acc[qt][vt] = f32x4{0.f, 0.f, 0.f, 0.f};
  float mrun[8], lrun[8];   // lrun: PER-LANE partial sums (16-lane reduce deferred to epilogue)
#pragma unroll
  for (int s = 0; s < 8; s++){ mrun[s] = -INFINITY; lrun[s] = 0.f; }

  for (int m0 = 0; m0 < M_; m0 += 32){
    // K fragments (B-frag: col = lane&15 -> m-row, k = (lane>>4)*8+i)
    s16x8 fkh[2][2], fkl[2][2];
#pragma unroll
    for (int mt = 0; mt < 2; mt++)
#pragma unroll
      for (int kc = 0; kc < 2; kc++){
        const int mr = m0 + mt * 16 + (lane & 15);
        const size_t off = (size_t)mr * 64 + kc * 32 + (lane >> 4) * 8;
        fkh[mt][kc] = *(const s16x8*)(kbh + off);
        fkl[mt][kc] = *(const s16x8*)(kbl + off);
      }
    // S tiles, split-3
    f32x4 S[2][2];
#pragma unroll
    for (int qt = 0; qt < 2; qt++)
#pragma unroll
      for (int mt = 0; mt < 2; mt++){
        f32x4 a = f32x4{0.f, 0.f, 0.f, 0.f};
        a = mfma16(fqh[qt][0], fkh[mt][0], a);
        a = mfma16(fqh[qt][1], fkh[mt][1], a);
        a = mfma16(fqh[qt][0], fkl[mt][0], a);
        a = mfma16(fqh[qt][1], fkl[mt][1], a);
        a = mfma16(fql[qt][0], fkh[mt][0], a);
        a = mfma16(fql[qt][1], fkh[mt][1], a);
        S[qt][mt] = a;
      }
    // + mask
#pragma unroll
    for (int qt = 0; qt < 2; qt++)
#pragma unroll
      for (int mt = 0; mt < 2; mt++)
#pragma unroll
        for (int r = 0; r < 4; r++){
          const int qq = q0 + qt * 16 + (lane >> 4) * 4 + r;
          const int mm = m0 + mt * 16 + (lane & 15);
          S[qt][mt][r] += mkb[(size_t)qq * M_ + mm];
        }
    // online softmax per row slot (8 slots); max reduced across the 16-lane
    // column group; SUM kept as per-lane partial (sc is group-uniform -> linear)
#pragma unroll
    for (int qt = 0; qt < 2; qt++)
#pragma unroll
      for (int r = 0; r < 4; r++){
        const int s = qt * 4 + r;
        float rmax = fmaxf(S[qt][0][r], S[qt][1][r]);
#pragma unroll
        for (int d = 1; d < 16; d <<= 1) rmax = fmaxf(rmax, __shfl_xor(rmax, d, 64));
        const float mnew = fmaxf(mrun[s], rmax);
        const float sc = __expf(mrun[s] - mnew);
        mrun[s] = mnew;
        const float p0 = __expf(S[qt][0][r] - mnew);
        const float p1 = __expf(S[qt][1][r] - mnew);
        lrun[s] = lrun[s] * sc + (p0 + p1);
#pragma unroll
        for (int vt = 0; vt < 4; vt++) acc[qt][vt][r] *= sc;
        const int qrow = qt * 16 + (lane >> 4) * 4 + r;
        pl[qrow * 40 + (lane & 15)]      = f2bf(p0);
        pl[qrow * 40 + 16 + (lane & 15)] = f2bf(p1);
      }
    // P A-frags from LDS (same-wave DS ordering; compiler inserts lgkmcnt wait)
    s16x8 pa[2];
#pragma unroll
    for (int qt = 0; qt < 2; qt++){
      const int off = (qt * 16 + (lane & 15)) * 80 + (lane >> 4) * 16;
      pa[qt] = *(const s16x8*)((const char*)pl + off);
    }
    // V B-frags from VT (b, v, m)
    s16x8 fv[4];
#pragma unroll
    for (int vt = 0; vt < 4; vt++){
      const int v = vt * 16 + (lane & 15);
      fv[vt] = *(const s16x8*)(vtb + (size_t)v * M_ + m0 + (lane >> 4) * 8);
    }
#pragma unroll
    for (int qt = 0; qt < 2; qt++)
#pragma unroll
      for (int vt = 0; vt < 4; vt++)
        acc[qt][vt] = mfma16(pa[qt], fv[vt], acc[qt][vt]);
  }

  // finalize: reduce deferred row sums across the 16-lane group, /l, split hi/lo,
  // store O' (b*N + q, h*64+v)
#pragma unroll
  for (int qt = 0; qt < 2; qt++)
#pragma unroll
    for (int r = 0; r < 4; r++){
      float tot = lrun[qt * 4 + r];
#pragma unroll
      for (int d = 1; d < 16; d <<= 1) tot += __shfl_xor(tot, d, 64);
      const float inv = 1.0f / tot;
#pragma unroll
      for (int vt = 0; vt < 4; vt++){
        const float v = acc[qt][vt][r] * inv;
        const int qq = q0 + qt * 16 + (lane >> 4) * 4 + r;
        const int vv = vt * 16 + (lane & 15);
        const size_t idx = ((size_t)(b * N_ + qq)) * 1024 + h * 64 + vv;
        u16 hh, ll; split2(v, hh, ll);
        Oh[idx] = hh; Ol[idx] = ll;
      }
    }
}

// ---------- host launcher ----------
extern "C" void kernel_launch(void* const* d_in, const int* in_sizes, int n_in,
                              void* d_out, int out_size, void* d_ws, size_t ws_size,
                              hipStream_t stream){
  const float* X  = (const float*)d_in[0];
  const float* Mi = (const float*)d_in[1];
  const float* mask = (const float*)d_in[2];
  const float* Pq = (const float*)d_in[3];
  const float* Pk = (const float*)d_in[4];
  const float* Pv = (const float*)d_in[5];
  const float* Po = (const float*)d_in[6];
  float* Y = (float*)d_out;

  char* ws = (char*)d_ws;
  auto alloc = [&](size_t bytes) -> char* {
    char* p = ws;
    ws += (bytes + 255) & ~(size_t)255;
    return p;
  };
  const size_t SZ_XM = (size_t)ROWS * D_ * 2;        // 16 MiB
  u16* Xh = (u16*)alloc(SZ_XM);
  u16* Xl = (u16*)alloc(SZ_XM);
  u16* Mh = (u16*)alloc(SZ_XM);
  u16* Ml = (u16*)alloc(SZ_XM);
  u16* PqTh = (u16*)alloc(1024 * 1024 * 2);
  u16* PqTl = (u16*)alloc(1024 * 1024 * 2);
  u16* PkvTh = (u16*)alloc(128 * 1024 * 2);
  u16* PkvTl = (u16*)alloc(128 * 1024 * 2);
  u16* WoTh = (u16*)alloc(1024 * 1024 * 2);
  u16* WoTl = (u16*)alloc(1024 * 1024 * 2);
  u16* Qh = (u16*)alloc(SZ_XM);
  u16* Ql = (u16*)alloc(SZ_XM);
  u16* Kh = (u16*)alloc((size_t)B_ * M_ * 64 * 2);
  u16* Kl = (u16*)alloc((size_t)B_ * M_ * 64 * 2);
  u16* VT = (u16*)alloc((size_t)B_ * M_ * 64 * 2);
  u16* Oh = (u16*)alloc(SZ_XM);
  u16* Ol = (u16*)alloc(SZ_XM);
  if ((size_t)(ws - (char*)d_ws) > ws_size) return;   // ws too small: output stays poisoned -> visible failure

  split_xm<<<2048, 256, 0, stream>>>(X, Mi, Xh, Xl, Mh, Ml);
  transform_w<<<1024, 256, 0, stream>>>(Pq, Pk, Pv, Po, PqTh, PqTl, PkvTh, PkvTl, WoTh, WoTl);
  gemm3<1><<<dim3(1, 64), 256, 0, stream>>>(Mh, Ml, PkvTh, PkvTl, Kh, Kl, VT);
  gemm3<0><<<dim3(8, 64), 256, 0, stream>>>(Xh, Xl, PqTh, PqTl, Qh, Ql, nullptr);
  attn<<<1024, 256, 0, stream>>>(Qh, Ql, Kh, Kl, VT, mask, Oh, Ol);
  gemm3<2><<<dim3(8, 64), 256, 0, stream>>>(Oh, Ol, WoTh, WoTl, Y, nullptr, nullptr);
}